// Round 2
// 262.539 us; speedup vs baseline: 1.0000x; 1.0000x over previous
//
#include <hip/hip_runtime.h>
#include <hip/hip_bf16.h>
#include <cstdint>

#define DIM 128
#define BK_SHIFT 7
#define BK_NODES 128          // nodes per bucket
#define MAX_BUCKETS 1024      // supports N <= 131072
#define CUR_STRIDE 16         // pad bucket cursors: 1 per 64B line
#define ST 4096               // edges per scatter block
#define EPT 16                // edges per thread (ST/256)
#define CAP 2560              // slack slots per bucket (mean 2046, >11 sigma margin)

typedef float f32x4  __attribute__((ext_vector_type(4)));
typedef short bf16x8 __attribute__((ext_vector_type(8)));   // 8 bf16 in 4 VGPRs

__device__ __forceinline__ unsigned bf16_rne(float f) {
    unsigned u = __float_as_uint(f);
    return (u + 0x7fffu + ((u >> 16) & 1u)) >> 16;   // round-to-nearest-even
}

// ---------------- dispatch 1: y = bf16(x) (unscaled) + Wt = bf16(W^T) + zero bcursor ----------------
// No dependency on the edge pipeline: dinv is applied per-edge in agg instead.
__global__ __launch_bounds__(256) void init_kernel(const float* __restrict__ x,
                                                   ushort* __restrict__ y,
                                                   const float* __restrict__ W,
                                                   ushort* __restrict__ Wt,
                                                   int* __restrict__ bcursor,
                                                   int N, int pb, int wb, int nbk) {
    int b = blockIdx.x, tid = threadIdx.x;
    if (b < pb) {
        int t = b * 256 + tid;                       // one float4 -> 4 bf16 (8B)
        if (t < N * (DIM / 4)) {
            float4 v = ((const float4*)x)[t];
            uint2 o;
            o.x = bf16_rne(v.x) | (bf16_rne(v.y) << 16);
            o.y = bf16_rne(v.z) | (bf16_rne(v.w) << 16);
            ((uint2*)y)[t] = o;
        }
    } else if (b < pb + wb) {
        int idx = (b - pb) * 256 + tid;
        if (idx < DIM * DIM) {
            int k = idx >> 7, c = idx & (DIM - 1);
            Wt[c * DIM + k] = (ushort)bf16_rne(W[idx]);
        }
    } else {
        int idx = (b - pb - wb) * 256 + tid;
        if (idx < nbk * CUR_STRIDE) bcursor[idx] = 0;
    }
}

// ---------------- dispatch 2: block-aggregated scatter into slack bucket regions ----------------
// LDS hist -> one reservation atomic per (block,bucket) on line-padded cursors
// (391-deep same-line chains, ~11.5 ns each => ~5 us) -> contiguous-run stores.
__global__ __launch_bounds__(256) void scatter_kernel(const int* __restrict__ src,
                                                      const int* __restrict__ dst,
                                                      int* __restrict__ bcursor,
                                                      int* __restrict__ bbuf,
                                                      int E, int nbk) {
    __shared__ int h[MAX_BUCKETS];   // count, then relative base
    for (int i = threadIdx.x; i < nbk; i += 256) h[i] = 0;
    __syncthreads();
    int base = blockIdx.x * ST;
    int bk[EPT], rk[EPT], pk[EPT];
    #pragma unroll
    for (int k = 0; k < EPT; ++k) {
        int e = base + k * 256 + threadIdx.x;
        bk[k] = -1;
        if (e < E) {
            int d = dst[e];
            int b = ((unsigned)d) >> BK_SHIFT;
            bk[k] = b;
            pk[k] = (src[e] << BK_SHIFT) | (d & (BK_NODES - 1));
            rk[k] = atomicAdd(&h[b], 1);
        }
    }
    __syncthreads();
    for (int i = threadIdx.x; i < nbk; i += 256) {
        int c = h[i];
        h[i] = c ? atomicAdd(&bcursor[i * CUR_STRIDE], c) : 0;   // relative base
    }
    __syncthreads();
    #pragma unroll
    for (int k = 0; k < EPT; ++k) {
        if (bk[k] >= 0) {
            int pos = h[bk[k]] + rk[k];
            if (pos < CAP) bbuf[(size_t)bk[k] * CAP + pos] = pk[k];
        }
    }
}

// ---------------- dispatch 3: per-bucket CSR build (obeg/oend, dinv, csr_src) ----------------
// Bucket count read directly from its cursor (hist+scan dispatches eliminated).
__global__ __launch_bounds__(256) void build_csr_kernel(const int* __restrict__ bbuf,
                                                        const int* __restrict__ bcursor,
                                                        int* __restrict__ obeg,
                                                        int* __restrict__ oend,
                                                        float* __restrict__ dinv,
                                                        int* __restrict__ csr_src,
                                                        int N) {
    __shared__ int cnt[BK_NODES];
    __shared__ int sc[BK_NODES];
    __shared__ int cur[BK_NODES];
    int b = blockIdx.x, tid = threadIdx.x;
    int count = bcursor[b * CUR_STRIDE];
    if (count > CAP) count = CAP;
    int base = b * CAP;
    if (tid < BK_NODES) cnt[tid] = 0;
    __syncthreads();
    for (int j = tid; j < count; j += 256)
        atomicAdd(&cnt[bbuf[base + j] & (BK_NODES - 1)], 1);
    __syncthreads();
    if (tid < BK_NODES) sc[tid] = cnt[tid];
    __syncthreads();
    for (int d = 1; d < BK_NODES; d <<= 1) {
        int v = (tid >= d && tid < BK_NODES) ? sc[tid - d] : 0;
        __syncthreads();
        if (tid < BK_NODES) sc[tid] += v;
        __syncthreads();
    }
    if (tid < BK_NODES) {
        int node = b * BK_NODES + tid;
        int start = base + sc[tid] - cnt[tid];
        cur[tid] = start;
        if (node < N) {
            obeg[node] = start;
            oend[node] = start + cnt[tid];
            dinv[node] = rsqrtf((float)(cnt[tid] + 1));   // +1 self loop
        }
    }
    __syncthreads();
    for (int j = tid; j < count; j += 256) {
        int p = bbuf[base + j];
        int pos = atomicAdd(&cur[p & (BK_NODES - 1)], 1);
        csr_src[pos] = p >> BK_SHIFT;
    }
}

// ---------------- dispatch 4: aggregation, wide-gather form ----------------
// One wave per node; 16 lanes per source row via dwordx4 (16B/lane):
//   - one vmem instruction fetches FOUR source rows (1KB), unroll x2 => 8 rows
//     (2KB) in flight per wave from 2 row-load instructions (old form: 12
//     dword loads per 4 rows, 1KB in flight, 3-deep dependent chain).
//   - lane (g = lane>>4, m = lane&15) accumulates channels [8m,8m+8) of slot
//     group g in f32; final 2-step __shfl_xor(16,32) butterfly sums the 4
//     groups; group 0 stores the 256B bf16 row.
//   - tail slots clamp the csr index to the last real edge with weight 0:
//     the clamped row was just loaded by this wave => L1-hot, no extra fetch.
__device__ __forceinline__ void agg_accum(float* a, uint4 v, float wt) {
    a[0] += wt * __uint_as_float(v.x << 16);
    a[1] += wt * __uint_as_float(v.x & 0xffff0000u);
    a[2] += wt * __uint_as_float(v.y << 16);
    a[3] += wt * __uint_as_float(v.y & 0xffff0000u);
    a[4] += wt * __uint_as_float(v.z << 16);
    a[5] += wt * __uint_as_float(v.z & 0xffff0000u);
    a[6] += wt * __uint_as_float(v.w << 16);
    a[7] += wt * __uint_as_float(v.w & 0xffff0000u);
}

__global__ __launch_bounds__(256) void agg_kernel(const ushort* __restrict__ y,
                                                  const int* __restrict__ csr_src,
                                                  const int* __restrict__ obeg,
                                                  const int* __restrict__ oend,
                                                  const float* __restrict__ dinv,
                                                  ushort* __restrict__ h, int N) {
    int lane = threadIdx.x & 63;
    int wid  = __builtin_amdgcn_readfirstlane((int)(threadIdx.x >> 6));
    int node = blockIdx.x * 4 + wid;
    if (node >= N) return;
    int g = lane >> 4;           // slot group 0..3 (which edge of a 4-pack)
    int m = lane & 15;           // 16B chunk within row: channels 8m..8m+7
    int beg = obeg[node];
    int cnt = oend[node] - beg;
    float di = dinv[node];
    float a[8];
    #pragma unroll
    for (int c = 0; c < 8; ++c) a[c] = 0.f;

    // self-loop term: weight di, counted once (group 0 only; same 256B row for
    // all four groups -> single-line broadcast load)
    {
        uint4 v = ((const uint4*)(y + (size_t)node * DIM))[m];
        agg_accum(a, v, (g == 0) ? di : 0.f);
    }

    int t = g;
    int nit = (cnt + 7) >> 3;    // 8 slots (2 packs of 4) per iteration
    for (int it = 0; it < nit; ++it, t += 8) {
        int tB = t + 4;
        int iA = beg + (t  < cnt ? t  : cnt - 1);
        int iB = beg + (tB < cnt ? tB : cnt - 1);
        int sA = csr_src[iA];
        int sB = csr_src[iB];
        float wA = (t  < cnt) ? dinv[sA] : 0.f;
        float wB = (tB < cnt) ? dinv[sB] : 0.f;
        uint4 vA = ((const uint4*)(y + (size_t)sA * DIM))[m];
        uint4 vB = ((const uint4*)(y + (size_t)sB * DIM))[m];
        agg_accum(a, vA, wA);
        agg_accum(a, vB, wB);
    }

    // combine the 4 slot groups: lanes m, m+16, m+32, m+48 hold partials of
    // the same 8 channels
    #pragma unroll
    for (int c = 0; c < 8; ++c) {
        a[c] += __shfl_xor(a[c], 16);
        a[c] += __shfl_xor(a[c], 32);
    }

    if (g == 0) {
        uint4 o;
        o.x = bf16_rne(di * a[0]) | (bf16_rne(di * a[1]) << 16);
        o.y = bf16_rne(di * a[2]) | (bf16_rne(di * a[3]) << 16);
        o.z = bf16_rne(di * a[4]) | (bf16_rne(di * a[5]) << 16);
        o.w = bf16_rne(di * a[6]) | (bf16_rne(di * a[7]) << 16);
        ((uint4*)(h + (size_t)node * DIM))[m] = o;
    }
}

// ---------------- dispatch 5: MFMA GEMM + bias + PReLU (R5 form, measured good) ----------------
__global__ __launch_bounds__(256) void gemm_kernel(const ushort* __restrict__ h,
                                                   const ushort* __restrict__ Wt,
                                                   const float* __restrict__ bias,
                                                   const float* __restrict__ alpha,
                                                   float* __restrict__ out, int N) {
    int lane = threadIdx.x & 63;
    int wv   = threadIdx.x >> 6;
    int rowbase = (blockIdx.x * 4 + wv) * 16;
    int r = lane & 15, quad = lane >> 4;
    f32x4 acc[8];
    #pragma unroll
    for (int ct = 0; ct < 8; ++ct) acc[ct] = (f32x4){0.f, 0.f, 0.f, 0.f};
    int arow = rowbase + r;
    if (arow >= N) arow = N - 1;
    const ushort* ap = h + (size_t)arow * DIM + quad * 8;
    #pragma unroll
    for (int ks = 0; ks < 4; ++ks) {
        bf16x8 a = *(const bf16x8*)(ap + ks * 32);
        #pragma unroll
        for (int ct = 0; ct < 8; ++ct) {
            bf16x8 b = *(const bf16x8*)(Wt + (size_t)(ct * 16 + r) * DIM + ks * 32 + quad * 8);
            acc[ct] = __builtin_amdgcn_mfma_f32_16x16x32_bf16(a, b, acc[ct], 0, 0, 0);
        }
    }
    #pragma unroll
    for (int ct = 0; ct < 8; ++ct) {
        int col = ct * 16 + r;
        float bb = bias[col], al = alpha[col];
        #pragma unroll
        for (int reg = 0; reg < 4; ++reg) {
            int grow = rowbase + quad * 4 + reg;
            if (grow < N) {
                float vv = acc[ct][reg] + bb;
                vv = vv > 0.f ? vv : al * vv;
                out[(size_t)grow * DIM + col] = vv;
            }
        }
    }
}

extern "C" void kernel_launch(void* const* d_in, const int* in_sizes, int n_in,
                              void* d_out, int out_size, void* d_ws, size_t ws_size,
                              hipStream_t stream) {
    const float* x     = (const float*)d_in[0];
    const int*   ei    = (const int*)d_in[1];
    const float* W     = (const float*)d_in[2];
    const float* bias  = (const float*)d_in[3];
    const float* alpha = (const float*)d_in[4];
    float* out = (float*)d_out;

    int N = in_sizes[0] / DIM;
    int E = in_sizes[1] / 2;
    const int* src = ei;
    const int* dst = ei + E;
    int nbk = (N + BK_NODES - 1) >> BK_SHIFT;   // 782

    char* ws = (char*)d_ws;
    size_t off = 0;
    auto alloc = [&](size_t bytes) -> char* {
        char* p = ws + off;
        off += (bytes + 255) & ~(size_t)255;
        return p;
    };
    // h region also hosts bbuf (8 MB), dead before agg writes h
    size_t h_bytes    = (size_t)N * DIM * 2;              // 25.6 MB
    size_t bbuf_bytes = (size_t)nbk * CAP * 4;            // 8.0 MB
    char*   hreg    = alloc(h_bytes > bbuf_bytes ? h_bytes : bbuf_bytes);
    ushort* h       = (ushort*)hreg;
    int*    bbuf    = (int*)hreg;
    int*    csr_src = (int*)alloc((size_t)nbk * CAP * 4); // 8.0 MB slack layout
    ushort* y       = (ushort*)alloc((size_t)N * DIM * 2);
    int*    bcursor = (int*)alloc((size_t)nbk * CUR_STRIDE * 4);
    int*    obeg    = (int*)alloc((size_t)N * 4);
    int*    oend    = (int*)alloc((size_t)N * 4);
    float*  dinv    = (float*)alloc((size_t)N * 4);
    ushort* Wt      = (ushort*)alloc((size_t)DIM * DIM * 2);
    // total ~60.5 MB (< 64.87 MB proven available in R4)

    int pb = (N * (DIM / 4) + 255) / 256;
    int wb = (DIM * DIM + 255) / 256;
    int zb = (nbk * CUR_STRIDE + 255) / 256;

    init_kernel<<<pb + wb + zb, 256, 0, stream>>>(x, y, W, Wt, bcursor, N, pb, wb, nbk);
    scatter_kernel<<<(E + ST - 1) / ST, 256, 0, stream>>>(src, dst, bcursor, bbuf, E, nbk);
    build_csr_kernel<<<nbk, 256, 0, stream>>>(bbuf, bcursor, obeg, oend, dinv, csr_src, N);
    agg_kernel<<<(N + 3) / 4, 256, 0, stream>>>(y, csr_src, obeg, oend, dinv, h, N);
    gemm_kernel<<<(N + 63) / 64, 256, 0, stream>>>(h, Wt, bias, alpha, out, N);
}

// Round 3
// 248.420 us; speedup vs baseline: 1.0568x; 1.0568x over previous
//
#include <hip/hip_runtime.h>
#include <hip/hip_bf16.h>
#include <cstdint>

#define DIM 128
#define BK_SHIFT 7
#define BK_NODES 128          // nodes per bucket
#define MAX_BUCKETS 1024      // supports N <= 131072
#define CUR_STRIDE 16         // pad bucket cursors: 1 per 64B line
#define ST 4096               // edges per scatter block
#define EPT 16                // edges per thread (ST/256)
#define CAP 2560              // slack slots per bucket (mean 2046, >11 sigma margin)
#define WPB 16                // waves (=nodes) per fused agg+gemm block

typedef float f32x4  __attribute__((ext_vector_type(4)));
typedef short bf16x8 __attribute__((ext_vector_type(8)));   // 8 bf16 in 4 VGPRs

__device__ __forceinline__ unsigned bf16_rne(float f) {
    unsigned u = __float_as_uint(f);
    return (u + 0x7fffu + ((u >> 16) & 1u)) >> 16;   // round-to-nearest-even
}

// ---------------- dispatch 1: y = bf16(x) (unscaled) + Wt = bf16(W^T) + zero bcursor ----------------
__global__ __launch_bounds__(256) void init_kernel(const float* __restrict__ x,
                                                   ushort* __restrict__ y,
                                                   const float* __restrict__ W,
                                                   ushort* __restrict__ Wt,
                                                   int* __restrict__ bcursor,
                                                   int N, int pb, int wb, int nbk) {
    int b = blockIdx.x, tid = threadIdx.x;
    if (b < pb) {
        int t = b * 256 + tid;                       // one float4 -> 4 bf16 (8B)
        if (t < N * (DIM / 4)) {
            float4 v = ((const float4*)x)[t];
            uint2 o;
            o.x = bf16_rne(v.x) | (bf16_rne(v.y) << 16);
            o.y = bf16_rne(v.z) | (bf16_rne(v.w) << 16);
            ((uint2*)y)[t] = o;
        }
    } else if (b < pb + wb) {
        int idx = (b - pb) * 256 + tid;
        if (idx < DIM * DIM) {
            int k = idx >> 7, c = idx & (DIM - 1);
            Wt[c * DIM + k] = (ushort)bf16_rne(W[idx]);
        }
    } else {
        int idx = (b - pb - wb) * 256 + tid;
        if (idx < nbk * CUR_STRIDE) bcursor[idx] = 0;
    }
}

// ---------------- dispatch 2: block-aggregated scatter into slack bucket regions ----------------
__global__ __launch_bounds__(256) void scatter_kernel(const int* __restrict__ src,
                                                      const int* __restrict__ dst,
                                                      int* __restrict__ bcursor,
                                                      int* __restrict__ bbuf,
                                                      int E, int nbk) {
    __shared__ int h[MAX_BUCKETS];   // count, then relative base
    for (int i = threadIdx.x; i < nbk; i += 256) h[i] = 0;
    __syncthreads();
    int base = blockIdx.x * ST;
    int bk[EPT], rk[EPT], pk[EPT];
    #pragma unroll
    for (int k = 0; k < EPT; ++k) {
        int e = base + k * 256 + threadIdx.x;
        bk[k] = -1;
        if (e < E) {
            int d = dst[e];
            int b = ((unsigned)d) >> BK_SHIFT;
            bk[k] = b;
            pk[k] = (src[e] << BK_SHIFT) | (d & (BK_NODES - 1));
            rk[k] = atomicAdd(&h[b], 1);
        }
    }
    __syncthreads();
    for (int i = threadIdx.x; i < nbk; i += 256) {
        int c = h[i];
        h[i] = c ? atomicAdd(&bcursor[i * CUR_STRIDE], c) : 0;   // relative base
    }
    __syncthreads();
    #pragma unroll
    for (int k = 0; k < EPT; ++k) {
        if (bk[k] >= 0) {
            int pos = h[bk[k]] + rk[k];
            if (pos < CAP) bbuf[(size_t)bk[k] * CAP + pos] = pk[k];
        }
    }
}

// ---------------- dispatch 3: per-bucket CSR build (obeg/oend, dinv, csr_src) ----------------
__global__ __launch_bounds__(256) void build_csr_kernel(const int* __restrict__ bbuf,
                                                        const int* __restrict__ bcursor,
                                                        int* __restrict__ obeg,
                                                        int* __restrict__ oend,
                                                        float* __restrict__ dinv,
                                                        int* __restrict__ csr_src,
                                                        int N) {
    __shared__ int cnt[BK_NODES];
    __shared__ int sc[BK_NODES];
    __shared__ int cur[BK_NODES];
    int b = blockIdx.x, tid = threadIdx.x;
    int count = bcursor[b * CUR_STRIDE];
    if (count > CAP) count = CAP;
    int base = b * CAP;
    if (tid < BK_NODES) cnt[tid] = 0;
    __syncthreads();
    for (int j = tid; j < count; j += 256)
        atomicAdd(&cnt[bbuf[base + j] & (BK_NODES - 1)], 1);
    __syncthreads();
    if (tid < BK_NODES) sc[tid] = cnt[tid];
    __syncthreads();
    for (int d = 1; d < BK_NODES; d <<= 1) {
        int v = (tid >= d && tid < BK_NODES) ? sc[tid - d] : 0;
        __syncthreads();
        if (tid < BK_NODES) sc[tid] += v;
        __syncthreads();
    }
    if (tid < BK_NODES) {
        int node = b * BK_NODES + tid;
        int start = base + sc[tid] - cnt[tid];
        cur[tid] = start;
        if (node < N) {
            obeg[node] = start;
            oend[node] = start + cnt[tid];
            dinv[node] = rsqrtf((float)(cnt[tid] + 1));   // +1 self loop
        }
    }
    __syncthreads();
    for (int j = tid; j < count; j += 256) {
        int p = bbuf[base + j];
        int pos = atomicAdd(&cur[p & (BK_NODES - 1)], 1);
        csr_src[pos] = p >> BK_SHIFT;
    }
}

// ---------------- dispatch 4: FUSED aggregation + MFMA GEMM + bias + PReLU ----------------
// Block = 1024 threads = 16 waves = 16 nodes. Each wave aggregates one node
// (identical wide-gather + numerics to the R2 agg_kernel) but stores the
// bf16-rounded row into a padded LDS tile instead of global h. After one
// barrier, waves 0-7 each compute one 16-column tile of the 16x128 GEMM
// (A-fragments from LDS, B-fragments from global Wt with the exact indexing
// of the proven standalone gemm), apply bias+PReLU, and store f32 out.
// Eliminates: the h round-trip (25.6 MB write + 25.6 MB read), one dispatch,
// and 4x of the per-wave Wt fragment re-reads. GEMM compute (4 MFMA/wave)
// hides under the fabric-bound gather of co-resident blocks.
__device__ __forceinline__ void agg_accum(float* a, uint4 v, float wt) {
    a[0] += wt * __uint_as_float(v.x << 16);
    a[1] += wt * __uint_as_float(v.x & 0xffff0000u);
    a[2] += wt * __uint_as_float(v.y << 16);
    a[3] += wt * __uint_as_float(v.y & 0xffff0000u);
    a[4] += wt * __uint_as_float(v.z << 16);
    a[5] += wt * __uint_as_float(v.z & 0xffff0000u);
    a[6] += wt * __uint_as_float(v.w << 16);
    a[7] += wt * __uint_as_float(v.w & 0xffff0000u);
}

__global__ __launch_bounds__(1024) void agg_gemm_kernel(const ushort* __restrict__ y,
                                                        const int* __restrict__ csr_src,
                                                        const int* __restrict__ obeg,
                                                        const int* __restrict__ oend,
                                                        const float* __restrict__ dinv,
                                                        const ushort* __restrict__ Wt,
                                                        const float* __restrict__ bias,
                                                        const float* __restrict__ alpha,
                                                        float* __restrict__ out, int N) {
    // 136-short row stride (272 B): keeps 16 B alignment for b128 ops and
    // breaks the worst same-bank row alignment.
    __shared__ ushort hT[WPB][136];
    int tid  = threadIdx.x;
    int lane = tid & 63;
    int wid  = __builtin_amdgcn_readfirstlane((int)(tid >> 6));   // 0..15
    int node = blockIdx.x * WPB + wid;
    int g = lane >> 4;           // slot group 0..3 (which edge of a 4-pack)
    int m = lane & 15;           // 16B chunk within row: channels 8m..8m+7

    float a[8];
    #pragma unroll
    for (int c = 0; c < 8; ++c) a[c] = 0.f;
    float di = 0.f;

    if (node < N) {
        int beg = obeg[node];
        int cnt = oend[node] - beg;
        di = dinv[node];

        // self-loop term (counted once via group-0 weight)
        {
            uint4 v = ((const uint4*)(y + (size_t)node * DIM))[m];
            agg_accum(a, v, (g == 0) ? di : 0.f);
        }

        int t = g;
        int nit = (cnt + 7) >> 3;    // 8 slots (2 packs of 4) per iteration
        for (int it = 0; it < nit; ++it, t += 8) {
            int tB = t + 4;
            int iA = beg + (t  < cnt ? t  : cnt - 1);
            int iB = beg + (tB < cnt ? tB : cnt - 1);
            int sA = csr_src[iA];
            int sB = csr_src[iB];
            float wA = (t  < cnt) ? dinv[sA] : 0.f;
            float wB = (tB < cnt) ? dinv[sB] : 0.f;
            uint4 vA = ((const uint4*)(y + (size_t)sA * DIM))[m];
            uint4 vB = ((const uint4*)(y + (size_t)sB * DIM))[m];
            agg_accum(a, vA, wA);
            agg_accum(a, vB, wB);
        }

        // combine the 4 slot groups
        #pragma unroll
        for (int c = 0; c < 8; ++c) {
            a[c] += __shfl_xor(a[c], 16);
            a[c] += __shfl_xor(a[c], 32);
        }
    }

    // bf16-rounded row -> LDS (zeros for node >= N; di=0 => a scaled to 0)
    if (g == 0) {
        uint4 o;
        o.x = bf16_rne(di * a[0]) | (bf16_rne(di * a[1]) << 16);
        o.y = bf16_rne(di * a[2]) | (bf16_rne(di * a[3]) << 16);
        o.z = bf16_rne(di * a[4]) | (bf16_rne(di * a[5]) << 16);
        o.w = bf16_rne(di * a[6]) | (bf16_rne(di * a[7]) << 16);
        *(uint4*)(&hT[wid][m * 8]) = o;
    }
    __syncthreads();

    // GEMM phase: waves 0-7, one 16-col tile each (ct = wid)
    if (wid < 8) {
        int r = lane & 15, quad = lane >> 4;
        int ct = wid;
        f32x4 acc = (f32x4){0.f, 0.f, 0.f, 0.f};
        #pragma unroll
        for (int ks = 0; ks < 4; ++ks) {
            bf16x8 av = *(const bf16x8*)(&hT[r][ks * 32 + quad * 8]);
            bf16x8 bv = *(const bf16x8*)(Wt + (size_t)(ct * 16 + r) * DIM + ks * 32 + quad * 8);
            acc = __builtin_amdgcn_mfma_f32_16x16x32_bf16(av, bv, acc, 0, 0, 0);
        }
        int col = ct * 16 + r;
        float bb = bias[col], al = alpha[col];
        int rowbase = blockIdx.x * WPB;
        #pragma unroll
        for (int reg = 0; reg < 4; ++reg) {
            int grow = rowbase + quad * 4 + reg;
            if (grow < N) {
                float vv = acc[reg] + bb;
                vv = vv > 0.f ? vv : al * vv;
                out[(size_t)grow * DIM + col] = vv;
            }
        }
    }
}

extern "C" void kernel_launch(void* const* d_in, const int* in_sizes, int n_in,
                              void* d_out, int out_size, void* d_ws, size_t ws_size,
                              hipStream_t stream) {
    const float* x     = (const float*)d_in[0];
    const int*   ei    = (const int*)d_in[1];
    const float* W     = (const float*)d_in[2];
    const float* bias  = (const float*)d_in[3];
    const float* alpha = (const float*)d_in[4];
    float* out = (float*)d_out;

    int N = in_sizes[0] / DIM;
    int E = in_sizes[1] / 2;
    const int* src = ei;
    const int* dst = ei + E;
    int nbk = (N + BK_NODES - 1) >> BK_SHIFT;   // 782

    char* ws = (char*)d_ws;
    size_t off = 0;
    auto alloc = [&](size_t bytes) -> char* {
        char* p = ws + off;
        off += (bytes + 255) & ~(size_t)255;
        return p;
    };
    int*    bbuf    = (int*)alloc((size_t)nbk * CAP * 4);    // 8.0 MB
    int*    csr_src = (int*)alloc((size_t)nbk * CAP * 4);    // 8.0 MB slack layout
    ushort* y       = (ushort*)alloc((size_t)N * DIM * 2);   // 25.6 MB
    int*    bcursor = (int*)alloc((size_t)nbk * CUR_STRIDE * 4);
    int*    obeg    = (int*)alloc((size_t)N * 4);
    int*    oend    = (int*)alloc((size_t)N * 4);
    float*  dinv    = (float*)alloc((size_t)N * 4);
    ushort* Wt      = (ushort*)alloc((size_t)DIM * DIM * 2);
    // total ~43 MB (< 64.87 MB proven available)

    int pb = (N * (DIM / 4) + 255) / 256;
    int wb = (DIM * DIM + 255) / 256;
    int zb = (nbk * CUR_STRIDE + 255) / 256;

    init_kernel<<<pb + wb + zb, 256, 0, stream>>>(x, y, W, Wt, bcursor, N, pb, wb, nbk);
    scatter_kernel<<<(E + ST - 1) / ST, 256, 0, stream>>>(src, dst, bcursor, bbuf, E, nbk);
    build_csr_kernel<<<nbk, 256, 0, stream>>>(bbuf, bcursor, obeg, oend, dinv, csr_src, N);
    agg_gemm_kernel<<<(N + WPB - 1) / WPB, 1024, 0, stream>>>(y, csr_src, obeg, oend, dinv,
                                                              Wt, bias, alpha, out, N);
}

// Round 4
// 241.626 us; speedup vs baseline: 1.0866x; 1.0281x over previous
//
#include <hip/hip_runtime.h>
#include <hip/hip_bf16.h>
#include <cstdint>

#define DIM 128
#define BK_SHIFT 7
#define BK_NODES 128          // nodes per bucket
#define MAX_BUCKETS 1024      // supports N <= 131072
#define CUR_STRIDE 16         // pad bucket cursors: 1 per 64B line
#define ST 4096               // edges per scatter block
#define EPT 16                // edges per thread (ST/256)
#define CAP 2560              // slack slots per bucket (mean 2046, >11 sigma margin)
#define WPB 64                // nodes per fused agg+gemm block (16 waves, dynamic)

typedef float f32x4  __attribute__((ext_vector_type(4)));
typedef short bf16x8 __attribute__((ext_vector_type(8)));   // 8 bf16 in 4 VGPRs

__device__ __forceinline__ unsigned bf16_rne(float f) {
    unsigned u = __float_as_uint(f);
    return (u + 0x7fffu + ((u >> 16) & 1u)) >> 16;   // round-to-nearest-even
}

// ---------------- dispatch 1: y = bf16(x) (unscaled) + Wt = bf16(W^T) + zero bcursor ----------------
__global__ __launch_bounds__(256) void init_kernel(const float* __restrict__ x,
                                                   ushort* __restrict__ y,
                                                   const float* __restrict__ W,
                                                   ushort* __restrict__ Wt,
                                                   int* __restrict__ bcursor,
                                                   int N, int pb, int wb, int nbk) {
    int b = blockIdx.x, tid = threadIdx.x;
    if (b < pb) {
        int t = b * 256 + tid;                       // one float4 -> 4 bf16 (8B)
        if (t < N * (DIM / 4)) {
            float4 v = ((const float4*)x)[t];
            uint2 o;
            o.x = bf16_rne(v.x) | (bf16_rne(v.y) << 16);
            o.y = bf16_rne(v.z) | (bf16_rne(v.w) << 16);
            ((uint2*)y)[t] = o;
        }
    } else if (b < pb + wb) {
        int idx = (b - pb) * 256 + tid;
        if (idx < DIM * DIM) {
            int k = idx >> 7, c = idx & (DIM - 1);
            Wt[c * DIM + k] = (ushort)bf16_rne(W[idx]);
        }
    } else {
        int idx = (b - pb - wb) * 256 + tid;
        if (idx < nbk * CUR_STRIDE) bcursor[idx] = 0;
    }
}

// ---------------- dispatch 2: block-aggregated scatter into slack bucket regions ----------------
__global__ __launch_bounds__(256) void scatter_kernel(const int* __restrict__ src,
                                                      const int* __restrict__ dst,
                                                      int* __restrict__ bcursor,
                                                      int* __restrict__ bbuf,
                                                      int E, int nbk) {
    __shared__ int h[MAX_BUCKETS];   // count, then relative base
    for (int i = threadIdx.x; i < nbk; i += 256) h[i] = 0;
    __syncthreads();
    int base = blockIdx.x * ST;
    int bk[EPT], rk[EPT], pk[EPT];
    #pragma unroll
    for (int k = 0; k < EPT; ++k) {
        int e = base + k * 256 + threadIdx.x;
        bk[k] = -1;
        if (e < E) {
            int d = dst[e];
            int b = ((unsigned)d) >> BK_SHIFT;
            bk[k] = b;
            pk[k] = (src[e] << BK_SHIFT) | (d & (BK_NODES - 1));
            rk[k] = atomicAdd(&h[b], 1);
        }
    }
    __syncthreads();
    for (int i = threadIdx.x; i < nbk; i += 256) {
        int c = h[i];
        h[i] = c ? atomicAdd(&bcursor[i * CUR_STRIDE], c) : 0;   // relative base
    }
    __syncthreads();
    #pragma unroll
    for (int k = 0; k < EPT; ++k) {
        if (bk[k] >= 0) {
            int pos = h[bk[k]] + rk[k];
            if (pos < CAP) bbuf[(size_t)bk[k] * CAP + pos] = pk[k];
        }
    }
}

// ---------------- dispatch 3: per-bucket CSR build (obeg/oend, dinv, csr_src) ----------------
__global__ __launch_bounds__(256) void build_csr_kernel(const int* __restrict__ bbuf,
                                                        const int* __restrict__ bcursor,
                                                        int* __restrict__ obeg,
                                                        int* __restrict__ oend,
                                                        float* __restrict__ dinv,
                                                        int* __restrict__ csr_src,
                                                        int N) {
    __shared__ int cnt[BK_NODES];
    __shared__ int sc[BK_NODES];
    __shared__ int cur[BK_NODES];
    int b = blockIdx.x, tid = threadIdx.x;
    int count = bcursor[b * CUR_STRIDE];
    if (count > CAP) count = CAP;
    int base = b * CAP;
    if (tid < BK_NODES) cnt[tid] = 0;
    __syncthreads();
    for (int j = tid; j < count; j += 256)
        atomicAdd(&cnt[bbuf[base + j] & (BK_NODES - 1)], 1);
    __syncthreads();
    if (tid < BK_NODES) sc[tid] = cnt[tid];
    __syncthreads();
    for (int d = 1; d < BK_NODES; d <<= 1) {
        int v = (tid >= d && tid < BK_NODES) ? sc[tid - d] : 0;
        __syncthreads();
        if (tid < BK_NODES) sc[tid] += v;
        __syncthreads();
    }
    if (tid < BK_NODES) {
        int node = b * BK_NODES + tid;
        int start = base + sc[tid] - cnt[tid];
        cur[tid] = start;
        if (node < N) {
            obeg[node] = start;
            oend[node] = start + cnt[tid];
            dinv[node] = rsqrtf((float)(cnt[tid] + 1));   // +1 self loop
        }
    }
    __syncthreads();
    for (int j = tid; j < count; j += 256) {
        int p = bbuf[base + j];
        int pos = atomicAdd(&cur[p & (BK_NODES - 1)], 1);
        csr_src[pos] = p >> BK_SHIFT;
    }
}

// ---------------- dispatch 4: FUSED aggregation + MFMA GEMM, load-balanced ----------------
// Block = 1024 threads = 16 waves, WPB=64 nodes. Nodes are assigned to waves
// DYNAMICALLY via an LDS counter (lane-0 atomicAdd + broadcast): block gather
// work ~ Poisson(1024) (sigma 3%), waves self-balance to within one node's
// tail -- removes the R3 barrier-straggler loss (max of 16 Poisson(16) gathers
// = ~40% idle). Per-node gather + numerics identical to R3. After one barrier,
// 32 GEMM tasks (4 row-tiles x 8 col-tiles) stripe over the 16 waves with the
// exact indexing of the proven gemm; bias+PReLU fused; f32 direct store.
__device__ __forceinline__ void agg_accum(float* a, uint4 v, float wt) {
    a[0] += wt * __uint_as_float(v.x << 16);
    a[1] += wt * __uint_as_float(v.x & 0xffff0000u);
    a[2] += wt * __uint_as_float(v.y << 16);
    a[3] += wt * __uint_as_float(v.y & 0xffff0000u);
    a[4] += wt * __uint_as_float(v.z << 16);
    a[5] += wt * __uint_as_float(v.z & 0xffff0000u);
    a[6] += wt * __uint_as_float(v.w << 16);
    a[7] += wt * __uint_as_float(v.w & 0xffff0000u);
}

__global__ __launch_bounds__(1024) void agg_gemm_kernel(const ushort* __restrict__ y,
                                                        const int* __restrict__ csr_src,
                                                        const int* __restrict__ obeg,
                                                        const int* __restrict__ oend,
                                                        const float* __restrict__ dinv,
                                                        const ushort* __restrict__ Wt,
                                                        const float* __restrict__ bias,
                                                        const float* __restrict__ alpha,
                                                        float* __restrict__ out, int N) {
    // 136-short row stride (272 B): 16B-aligned for b128, breaks worst
    // same-bank row alignment (R3: 800K conflict cycles, not dominant).
    __shared__ ushort hT[WPB][136];
    __shared__ int nodectr;
    int tid  = threadIdx.x;
    int lane = tid & 63;
    int g = lane >> 4;           // slot group 0..3 (which edge of a 4-pack)
    int m = lane & 15;           // 16B chunk within row: channels 8m..8m+7
    if (tid == 0) nodectr = 0;
    __syncthreads();

    // ---- gather phase: dynamic node grab ----
    for (;;) {
        int local;
        if (lane == 0) local = atomicAdd(&nodectr, 1);
        local = __builtin_amdgcn_readfirstlane(local);
        if (local >= WPB) break;
        int node = blockIdx.x * WPB + local;

        float a[8];
        #pragma unroll
        for (int c = 0; c < 8; ++c) a[c] = 0.f;
        float di = 0.f;

        if (node < N) {
            int beg = obeg[node];
            int cnt = oend[node] - beg;
            di = dinv[node];

            // self-loop term (counted once via group-0 weight)
            {
                uint4 v = ((const uint4*)(y + (size_t)node * DIM))[m];
                agg_accum(a, v, (g == 0) ? di : 0.f);
            }

            int t = g;
            int nit = (cnt + 7) >> 3;    // 8 slots (2 packs of 4) per iteration
            for (int it = 0; it < nit; ++it, t += 8) {
                int tB = t + 4;
                int iA = beg + (t  < cnt ? t  : cnt - 1);
                int iB = beg + (tB < cnt ? tB : cnt - 1);
                int sA = csr_src[iA];
                int sB = csr_src[iB];
                float wA = (t  < cnt) ? dinv[sA] : 0.f;
                float wB = (tB < cnt) ? dinv[sB] : 0.f;
                uint4 vA = ((const uint4*)(y + (size_t)sA * DIM))[m];
                uint4 vB = ((const uint4*)(y + (size_t)sB * DIM))[m];
                agg_accum(a, vA, wA);
                agg_accum(a, vB, wB);
            }

            // combine the 4 slot groups
            #pragma unroll
            for (int c = 0; c < 8; ++c) {
                a[c] += __shfl_xor(a[c], 16);
                a[c] += __shfl_xor(a[c], 32);
            }
        }

        // bf16-rounded row -> LDS (zeros for node >= N; di=0 => scaled to 0)
        if (g == 0) {
            uint4 o;
            o.x = bf16_rne(di * a[0]) | (bf16_rne(di * a[1]) << 16);
            o.y = bf16_rne(di * a[2]) | (bf16_rne(di * a[3]) << 16);
            o.z = bf16_rne(di * a[4]) | (bf16_rne(di * a[5]) << 16);
            o.w = bf16_rne(di * a[6]) | (bf16_rne(di * a[7]) << 16);
            *(uint4*)(&hT[local][m * 8]) = o;
        }
    }
    __syncthreads();

    // ---- GEMM phase: 32 tasks (rt 0..3, ct 0..7) over 16 waves ----
    int wid = __builtin_amdgcn_readfirstlane((int)(tid >> 6));
    int r = lane & 15, quad = lane >> 4;
    for (int task = wid; task < 32; task += 16) {
        int rt = task >> 3, ct = task & 7;
        f32x4 acc = (f32x4){0.f, 0.f, 0.f, 0.f};
        #pragma unroll
        for (int ks = 0; ks < 4; ++ks) {
            bf16x8 av = *(const bf16x8*)(&hT[rt * 16 + r][ks * 32 + quad * 8]);
            bf16x8 bv = *(const bf16x8*)(Wt + (size_t)(ct * 16 + r) * DIM + ks * 32 + quad * 8);
            acc = __builtin_amdgcn_mfma_f32_16x16x32_bf16(av, bv, acc, 0, 0, 0);
        }
        int col = ct * 16 + r;
        float bb = bias[col], al = alpha[col];
        int rowbase = blockIdx.x * WPB + rt * 16;
        #pragma unroll
        for (int reg = 0; reg < 4; ++reg) {
            int grow = rowbase + quad * 4 + reg;
            if (grow < N) {
                float vv = acc[reg] + bb;
                vv = vv > 0.f ? vv : al * vv;
                out[(size_t)grow * DIM + col] = vv;
            }
        }
    }
}

extern "C" void kernel_launch(void* const* d_in, const int* in_sizes, int n_in,
                              void* d_out, int out_size, void* d_ws, size_t ws_size,
                              hipStream_t stream) {
    const float* x     = (const float*)d_in[0];
    const int*   ei    = (const int*)d_in[1];
    const float* W     = (const float*)d_in[2];
    const float* bias  = (const float*)d_in[3];
    const float* alpha = (const float*)d_in[4];
    float* out = (float*)d_out;

    int N = in_sizes[0] / DIM;
    int E = in_sizes[1] / 2;
    const int* src = ei;
    const int* dst = ei + E;
    int nbk = (N + BK_NODES - 1) >> BK_SHIFT;   // 782

    char* ws = (char*)d_ws;
    size_t off = 0;
    auto alloc = [&](size_t bytes) -> char* {
        char* p = ws + off;
        off += (bytes + 255) & ~(size_t)255;
        return p;
    };
    int*    bbuf    = (int*)alloc((size_t)nbk * CAP * 4);    // 8.0 MB
    int*    csr_src = (int*)alloc((size_t)nbk * CAP * 4);    // 8.0 MB slack layout
    ushort* y       = (ushort*)alloc((size_t)N * DIM * 2);   // 25.6 MB
    int*    bcursor = (int*)alloc((size_t)nbk * CUR_STRIDE * 4);
    int*    obeg    = (int*)alloc((size_t)N * 4);
    int*    oend    = (int*)alloc((size_t)N * 4);
    float*  dinv    = (float*)alloc((size_t)N * 4);
    ushort* Wt      = (ushort*)alloc((size_t)DIM * DIM * 2);
    // total ~43 MB (< 64.87 MB proven available)

    int pb = (N * (DIM / 4) + 255) / 256;
    int wb = (DIM * DIM + 255) / 256;
    int zb = (nbk * CUR_STRIDE + 255) / 256;

    init_kernel<<<pb + wb + zb, 256, 0, stream>>>(x, y, W, Wt, bcursor, N, pb, wb, nbk);
    scatter_kernel<<<(E + ST - 1) / ST, 256, 0, stream>>>(src, dst, bcursor, bbuf, E, nbk);
    build_csr_kernel<<<nbk, 256, 0, stream>>>(bbuf, bcursor, obeg, oend, dinv, csr_src, N);
    agg_gemm_kernel<<<(N + WPB - 1) / WPB, 1024, 0, stream>>>(y, csr_src, obeg, oend, dinv,
                                                              Wt, bias, alpha, out, N);
}

// Round 5
// 228.027 us; speedup vs baseline: 1.1514x; 1.0596x over previous
//
#include <hip/hip_runtime.h>
#include <hip/hip_bf16.h>
#include <cstdint>

#define DIM 128
#define BK_SHIFT 7
#define BK_NODES 128          // nodes per bucket
#define MAX_BUCKETS 1024      // supports N <= 131072
#define CUR_STRIDE 16         // pad bucket cursors: 1 per 64B line
#define ST 16384              // edges per scatter block (98 blocks -> 98-deep chains, was 391)
#define EPT 16                // edges per thread (ST/1024)
#define CAP 2560              // slack slots per bucket (mean 2046, >11 sigma margin)
#define WPB 64                // nodes per fused tile
#define PERSIST_BLOCKS 512    // 2 blocks/CU, persistent; tiles via global counter

typedef float f32x4  __attribute__((ext_vector_type(4)));
typedef short bf16x8 __attribute__((ext_vector_type(8)));   // 8 bf16 in 4 VGPRs

__device__ __forceinline__ unsigned bf16_rne(float f) {
    unsigned u = __float_as_uint(f);
    return (u + 0x7fffu + ((u >> 16) & 1u)) >> 16;   // round-to-nearest-even
}

// ---------------- dispatch 1: y = bf16(x) (unscaled) + Wt = bf16(W^T) + zero bcursor+gctr ----------------
__global__ __launch_bounds__(256) void init_kernel(const float* __restrict__ x,
                                                   ushort* __restrict__ y,
                                                   const float* __restrict__ W,
                                                   ushort* __restrict__ Wt,
                                                   int* __restrict__ bcursor,
                                                   int N, int pb, int wb, int nbk) {
    int b = blockIdx.x, tid = threadIdx.x;
    if (b < pb) {
        int t = b * 256 + tid;                       // one float4 -> 4 bf16 (8B)
        if (t < N * (DIM / 4)) {
            float4 v = ((const float4*)x)[t];
            uint2 o;
            o.x = bf16_rne(v.x) | (bf16_rne(v.y) << 16);
            o.y = bf16_rne(v.z) | (bf16_rne(v.w) << 16);
            ((uint2*)y)[t] = o;
        }
    } else if (b < pb + wb) {
        int idx = (b - pb) * 256 + tid;
        if (idx < DIM * DIM) {
            int k = idx >> 7, c = idx & (DIM - 1);
            Wt[c * DIM + k] = (ushort)bf16_rne(W[idx]);
        }
    } else {
        int idx = (b - pb - wb) * 256 + tid;
        if (idx < nbk * CUR_STRIDE + 16) bcursor[idx] = 0;   // +16: global tile ctr line
    }
}

// ---------------- dispatch 2: block-aggregated scatter into slack bucket regions ----------------
// 1024 threads, ST=16384: 98 blocks instead of 391 -> 4x shallower same-line
// global-atomic reservation chains and 4x longer contiguous bbuf runs.
__global__ __launch_bounds__(1024) void scatter_kernel(const int* __restrict__ src,
                                                       const int* __restrict__ dst,
                                                       int* __restrict__ bcursor,
                                                       int* __restrict__ bbuf,
                                                       int E, int nbk) {
    __shared__ int h[MAX_BUCKETS];   // count, then relative base
    for (int i = threadIdx.x; i < nbk; i += 1024) h[i] = 0;
    __syncthreads();
    int base = blockIdx.x * ST;
    int bk[EPT], rk[EPT], pk[EPT];
    #pragma unroll
    for (int k = 0; k < EPT; ++k) {
        int e = base + k * 1024 + threadIdx.x;
        bk[k] = -1;
        if (e < E) {
            int d = dst[e];
            int b = ((unsigned)d) >> BK_SHIFT;
            bk[k] = b;
            pk[k] = (src[e] << BK_SHIFT) | (d & (BK_NODES - 1));
            rk[k] = atomicAdd(&h[b], 1);
        }
    }
    __syncthreads();
    for (int i = threadIdx.x; i < nbk; i += 1024) {
        int c = h[i];
        h[i] = c ? atomicAdd(&bcursor[i * CUR_STRIDE], c) : 0;   // relative base
    }
    __syncthreads();
    #pragma unroll
    for (int k = 0; k < EPT; ++k) {
        if (bk[k] >= 0) {
            int pos = h[bk[k]] + rk[k];
            if (pos < CAP) bbuf[(size_t)bk[k] * CAP + pos] = pk[k];
        }
    }
}

// ---------------- dispatch 3: per-bucket CSR build (obeg/oend, dinv, csr_src) ----------------
__global__ __launch_bounds__(256) void build_csr_kernel(const int* __restrict__ bbuf,
                                                        const int* __restrict__ bcursor,
                                                        int* __restrict__ obeg,
                                                        int* __restrict__ oend,
                                                        float* __restrict__ dinv,
                                                        int* __restrict__ csr_src,
                                                        int N) {
    __shared__ int cnt[BK_NODES];
    __shared__ int sc[BK_NODES];
    __shared__ int cur[BK_NODES];
    int b = blockIdx.x, tid = threadIdx.x;
    int count = bcursor[b * CUR_STRIDE];
    if (count > CAP) count = CAP;
    int base = b * CAP;
    if (tid < BK_NODES) cnt[tid] = 0;
    __syncthreads();
    for (int j = tid; j < count; j += 256)
        atomicAdd(&cnt[bbuf[base + j] & (BK_NODES - 1)], 1);
    __syncthreads();
    if (tid < BK_NODES) sc[tid] = cnt[tid];
    __syncthreads();
    for (int d = 1; d < BK_NODES; d <<= 1) {
        int v = (tid >= d && tid < BK_NODES) ? sc[tid - d] : 0;
        __syncthreads();
        if (tid < BK_NODES) sc[tid] += v;
        __syncthreads();
    }
    if (tid < BK_NODES) {
        int node = b * BK_NODES + tid;
        int start = base + sc[tid] - cnt[tid];
        cur[tid] = start;
        if (node < N) {
            obeg[node] = start;
            oend[node] = start + cnt[tid];
            dinv[node] = rsqrtf((float)(cnt[tid] + 1));   // +1 self loop
        }
    }
    __syncthreads();
    for (int j = tid; j < count; j += 256) {
        int p = bbuf[base + j];
        int pos = atomicAdd(&cur[p & (BK_NODES - 1)], 1);
        csr_src[pos] = p >> BK_SHIFT;
    }
}

// ---------------- dispatch 4: FUSED agg + GEMM, persistent blocks + reg-resident Wt ----------------
// 512 persistent blocks (2/CU) grab 64-node tiles from a GLOBAL counter:
// removes the R4 grid-quantization loss (1563 blocks / 512 resident = 3.05
// rounds -> 4th round at 5% utilization = the measured 2.63-vs-3.34 TB/s gap).
// Static GEMM pairing: wave wid owns column-tile ct=wid&7 for row-tiles
// rt0=wid>>3 and rt0+2 -> ONE B-fragment set (16 VGPRs) + bias/alpha,
// preloaded once per kernel: the per-tile GEMM phase has ZERO global loads.
__device__ __forceinline__ void agg_accum(float* a, uint4 v, float wt) {
    a[0] += wt * __uint_as_float(v.x << 16);
    a[1] += wt * __uint_as_float(v.x & 0xffff0000u);
    a[2] += wt * __uint_as_float(v.y << 16);
    a[3] += wt * __uint_as_float(v.y & 0xffff0000u);
    a[4] += wt * __uint_as_float(v.z << 16);
    a[5] += wt * __uint_as_float(v.z & 0xffff0000u);
    a[6] += wt * __uint_as_float(v.w << 16);
    a[7] += wt * __uint_as_float(v.w & 0xffff0000u);
}

__global__ __launch_bounds__(1024) void agg_gemm_kernel(const ushort* __restrict__ y,
                                                        const int* __restrict__ csr_src,
                                                        const int* __restrict__ obeg,
                                                        const int* __restrict__ oend,
                                                        const float* __restrict__ dinv,
                                                        const ushort* __restrict__ Wt,
                                                        const float* __restrict__ bias,
                                                        const float* __restrict__ alpha,
                                                        float* __restrict__ out,
                                                        int* __restrict__ gctr,
                                                        int N, int ntiles) {
    __shared__ ushort hT[WPB][136];   // 272B row stride: 16B-aligned, bank-spread
    __shared__ int s_tile, nodectr;
    int tid  = threadIdx.x;
    int lane = tid & 63;
    int wid  = __builtin_amdgcn_readfirstlane((int)(tid >> 6));   // 0..15
    int g = lane >> 4;           // slot group / quad
    int m = lane & 15;           // 16B chunk / row-in-tile

    // preload: B fragment for this wave's column tile + epilogue constants
    int ct  = wid & 7;
    int rt0 = wid >> 3;
    bf16x8 bfrag[4];
    #pragma unroll
    for (int ks = 0; ks < 4; ++ks)
        bfrag[ks] = *(const bf16x8*)(Wt + (size_t)(ct * 16 + m) * DIM + ks * 32 + g * 8);
    int col = ct * 16 + m;
    float bb = bias[col], al = alpha[col];

    for (;;) {
        __syncthreads();                       // prev GEMM done: hT/nodectr free
        if (tid == 0) { s_tile = atomicAdd(gctr, 1); nodectr = 0; }
        __syncthreads();
        int tile = s_tile;
        if (tile >= ntiles) break;
        int nbase = tile * WPB;

        // ---- gather phase: dynamic node grab within tile ----
        for (;;) {
            int local;
            if (lane == 0) local = atomicAdd(&nodectr, 1);
            local = __builtin_amdgcn_readfirstlane(local);
            if (local >= WPB) break;
            int node = nbase + local;

            float a[8];
            #pragma unroll
            for (int c = 0; c < 8; ++c) a[c] = 0.f;
            float di = 0.f;

            if (node < N) {
                int beg = obeg[node];
                int cnt = oend[node] - beg;
                di = dinv[node];

                {   // self-loop (counted once via group-0 weight)
                    uint4 v = ((const uint4*)(y + (size_t)node * DIM))[m];
                    agg_accum(a, v, (g == 0) ? di : 0.f);
                }

                int t = g;
                int nit = (cnt + 7) >> 3;    // 8 slots (2 packs of 4) per iter
                for (int it = 0; it < nit; ++it, t += 8) {
                    int tB = t + 4;
                    int iA = beg + (t  < cnt ? t  : cnt - 1);
                    int iB = beg + (tB < cnt ? tB : cnt - 1);
                    int sA = csr_src[iA];
                    int sB = csr_src[iB];
                    float wA = (t  < cnt) ? dinv[sA] : 0.f;
                    float wB = (tB < cnt) ? dinv[sB] : 0.f;
                    uint4 vA = ((const uint4*)(y + (size_t)sA * DIM))[m];
                    uint4 vB = ((const uint4*)(y + (size_t)sB * DIM))[m];
                    agg_accum(a, vA, wA);
                    agg_accum(a, vB, wB);
                }

                #pragma unroll
                for (int c = 0; c < 8; ++c) {
                    a[c] += __shfl_xor(a[c], 16);
                    a[c] += __shfl_xor(a[c], 32);
                }
            }

            if (g == 0) {        // bf16 row -> LDS (zeros for node >= N)
                uint4 o;
                o.x = bf16_rne(di * a[0]) | (bf16_rne(di * a[1]) << 16);
                o.y = bf16_rne(di * a[2]) | (bf16_rne(di * a[3]) << 16);
                o.z = bf16_rne(di * a[4]) | (bf16_rne(di * a[5]) << 16);
                o.w = bf16_rne(di * a[6]) | (bf16_rne(di * a[7]) << 16);
                *(uint4*)(&hT[local][m * 8]) = o;
            }
        }
        __syncthreads();

        // ---- GEMM phase: 2 tasks/wave, zero global loads ----
        #pragma unroll
        for (int tt = 0; tt < 2; ++tt) {
            int rt = rt0 + tt * 2;
            f32x4 acc = (f32x4){0.f, 0.f, 0.f, 0.f};
            #pragma unroll
            for (int ks = 0; ks < 4; ++ks) {
                bf16x8 av = *(const bf16x8*)(&hT[rt * 16 + m][ks * 32 + g * 8]);
                acc = __builtin_amdgcn_mfma_f32_16x16x32_bf16(av, bfrag[ks], acc, 0, 0, 0);
            }
            int rowbase = nbase + rt * 16;
            #pragma unroll
            for (int reg = 0; reg < 4; ++reg) {
                int grow = rowbase + g * 4 + reg;
                if (grow < N) {
                    float vv = acc[reg] + bb;
                    vv = vv > 0.f ? vv : al * vv;
                    out[(size_t)grow * DIM + col] = vv;
                }
            }
        }
    }
}

extern "C" void kernel_launch(void* const* d_in, const int* in_sizes, int n_in,
                              void* d_out, int out_size, void* d_ws, size_t ws_size,
                              hipStream_t stream) {
    const float* x     = (const float*)d_in[0];
    const int*   ei    = (const int*)d_in[1];
    const float* W     = (const float*)d_in[2];
    const float* bias  = (const float*)d_in[3];
    const float* alpha = (const float*)d_in[4];
    float* out = (float*)d_out;

    int N = in_sizes[0] / DIM;
    int E = in_sizes[1] / 2;
    const int* src = ei;
    const int* dst = ei + E;
    int nbk = (N + BK_NODES - 1) >> BK_SHIFT;   // 782
    int ntiles = (N + WPB - 1) / WPB;           // 1563

    char* ws = (char*)d_ws;
    size_t off = 0;
    auto alloc = [&](size_t bytes) -> char* {
        char* p = ws + off;
        off += (bytes + 255) & ~(size_t)255;
        return p;
    };
    int*    bbuf    = (int*)alloc((size_t)nbk * CAP * 4);    // 8.0 MB
    int*    csr_src = (int*)alloc((size_t)nbk * CAP * 4);    // 8.0 MB slack layout
    ushort* y       = (ushort*)alloc((size_t)N * DIM * 2);   // 25.6 MB
    int*    bcursor = (int*)alloc(((size_t)nbk * CUR_STRIDE + 16) * 4);  // +gctr line
    int*    obeg    = (int*)alloc((size_t)N * 4);
    int*    oend    = (int*)alloc((size_t)N * 4);
    float*  dinv    = (float*)alloc((size_t)N * 4);
    ushort* Wt      = (ushort*)alloc((size_t)DIM * DIM * 2);
    int*    gctr    = bcursor + (size_t)nbk * CUR_STRIDE;
    // total ~43 MB (< 64.87 MB proven available)

    int pb = (N * (DIM / 4) + 255) / 256;
    int wb = (DIM * DIM + 255) / 256;
    int zb = (nbk * CUR_STRIDE + 16 + 255) / 256;

    init_kernel<<<pb + wb + zb, 256, 0, stream>>>(x, y, W, Wt, bcursor, N, pb, wb, nbk);
    scatter_kernel<<<(E + ST - 1) / ST, 1024, 0, stream>>>(src, dst, bcursor, bbuf, E, nbk);
    build_csr_kernel<<<nbk, 256, 0, stream>>>(bbuf, bcursor, obeg, oend, dinv, csr_src, N);
    agg_gemm_kernel<<<PERSIST_BLOCKS, 1024, 0, stream>>>(y, csr_src, obeg, oend, dinv,
                                                         Wt, bias, alpha, out, gctr, N, ntiles);
}